// Round 1
// baseline (1574.507 us; speedup 1.0000x reference)
//
#include <hip/hip_runtime.h>
#include <hip/hip_bf16.h>

#define B_ 16
#define T_ 32
#define NS_ 10
#define D_ 128
#define ST_ 512
#define V_ 32000
#define NCHAIN 160

using short8 = __attribute__((ext_vector_type(8))) short;
using f32x4  = __attribute__((ext_vector_type(4))) float;

__device__ __forceinline__ unsigned short f2bf(float f){
  unsigned u = __float_as_uint(f);
  u += 0x7FFFu + ((u >> 16) & 1u);          // RNE to bf16
  return (unsigned short)(u >> 16);
}
__device__ __forceinline__ unsigned packbf(float a, float b){
  return ((unsigned)f2bf(b) << 16) | (unsigned)f2bf(a);
}
__device__ __forceinline__ void mac2(unsigned ux, unsigned ul, unsigned uh,
                                     float& a1, float& a2){
  const float x0 = __uint_as_float(ux << 16);
  const float x1 = __uint_as_float(ux & 0xFFFF0000u);
  const float l0 = __uint_as_float(ul << 16);
  const float l1 = __uint_as_float(ul & 0xFFFF0000u);
  const float h0 = __uint_as_float(uh << 16);
  const float h1 = __uint_as_float(uh & 0xFFFF0000u);
  a1 = fmaf(x1, l1, fmaf(x0, l0, a1));
  a2 = fmaf(x1, h1, fmaf(x0, h0, a2));
}

// ---------------------------------------------------------------------------
// Phase B: partial[s] = sum_v exp(move_s . vocabW_v + vb_v)   (512x32000 GEMM)
// grid (125,8); block 256 = 4 waves; block covers 64 states x 1024 vocab rows.
// mfma_f32_16x16x32_bf16: A lane l -> A[row=l&15][k=(l>>4)*8+j]
//                         B lane l -> B[k=(l>>4)*8+j][col=l&15]
//                         D lane l -> D[row=(l>>4)*4+r][col=l&15]
// ---------------------------------------------------------------------------
__global__ __launch_bounds__(256) void logz_kernel(
    const float* __restrict__ move, const float* __restrict__ vw,
    const float* __restrict__ vb, float* __restrict__ partial)
{
  const int sg = blockIdx.y;
  const int vc = blockIdx.x;
  const int wv = threadIdx.x >> 6;
  const int lane = threadIdx.x & 63;
  const int c16 = lane & 15, q = lane >> 4;

  __shared__ float les[64];
  if (threadIdx.x < 64) les[threadIdx.x] = 0.f;

  short8 afr[4][4];
  #pragma unroll
  for (int rt = 0; rt < 4; ++rt){
    const float* mp = move + (sg*64 + rt*16 + c16)*D_ + q*8;
    #pragma unroll
    for (int kk = 0; kk < 4; ++kk){
      float4 f0 = *(const float4*)(mp + kk*32);
      float4 f1 = *(const float4*)(mp + kk*32 + 4);
      short8 a;
      a[0]=(short)f2bf(f0.x); a[1]=(short)f2bf(f0.y);
      a[2]=(short)f2bf(f0.z); a[3]=(short)f2bf(f0.w);
      a[4]=(short)f2bf(f1.x); a[5]=(short)f2bf(f1.y);
      a[6]=(short)f2bf(f1.z); a[7]=(short)f2bf(f1.w);
      afr[rt][kk] = a;
    }
  }
  __syncthreads();   // les initialized before any LDS atomicAdd below

  float es[4][4] = {{0.f,0.f,0.f,0.f},{0.f,0.f,0.f,0.f},
                    {0.f,0.f,0.f,0.f},{0.f,0.f,0.f,0.f}};

  for (int it = 0; it < 4; ++it){
    const int vt = vc*256 + it*64 + wv*16;
    const int v  = vt + c16;
    const float* wp = vw + v*D_ + q*8;
    short8 bfr[4];
    #pragma unroll
    for (int kk = 0; kk < 4; ++kk){
      float4 f0 = *(const float4*)(wp + kk*32);
      float4 f1 = *(const float4*)(wp + kk*32 + 4);
      short8 bb;
      bb[0]=(short)f2bf(f0.x); bb[1]=(short)f2bf(f0.y);
      bb[2]=(short)f2bf(f0.z); bb[3]=(short)f2bf(f0.w);
      bb[4]=(short)f2bf(f1.x); bb[5]=(short)f2bf(f1.y);
      bb[6]=(short)f2bf(f1.z); bb[7]=(short)f2bf(f1.w);
      bfr[kk] = bb;
    }
    const float bias = vb[v];
    #pragma unroll
    for (int rt = 0; rt < 4; ++rt){
      f32x4 acc = {0.f, 0.f, 0.f, 0.f};
      #pragma unroll
      for (int kk = 0; kk < 4; ++kk)
        acc = __builtin_amdgcn_mfma_f32_16x16x32_bf16(afr[rt][kk], bfr[kk], acc, 0, 0, 0);
      #pragma unroll
      for (int r = 0; r < 4; ++r)
        es[rt][r] += __expf(acc[r] + bias);   // logits ~ +-0.2, no max needed
    }
  }
  // reduce over the 16 columns (lanes differing in low 4 bits share a row)
  #pragma unroll
  for (int m = 1; m < 16; m <<= 1){
    #pragma unroll
    for (int rt = 0; rt < 4; ++rt)
      #pragma unroll
      for (int r = 0; r < 4; ++r)
        es[rt][r] += __shfl_xor(es[rt][r], m, 64);
  }
  if (c16 == 0){
    #pragma unroll
    for (int rt = 0; rt < 4; ++rt)
      #pragma unroll
      for (int r = 0; r < 4; ++r)
        atomicAdd(&les[rt*16 + q*4 + r], es[rt][r]);
  }
  __syncthreads();
  if (threadIdx.x < 64) atomicAdd(&partial[sg*64 + threadIdx.x], les[threadIdx.x]);
}

// ---------------------------------------------------------------------------
// Phase A: the sequential 32-step scan. One block per (b, sample) chain.
// 512 threads; thread t owns state row t of state_pref_W (bf16-packed in regs).
// prev1 = W[:, :128].znorm from previous step == W[:, :128].zold this step.
// ---------------------------------------------------------------------------
__global__ __launch_bounds__(512) void scan_kernel(
    const int* __restrict__ zi, const float* __restrict__ latent,
    const float* __restrict__ prefW, const float* __restrict__ prefB,
    const float* __restrict__ move, const float* __restrict__ rd,
    int* __restrict__ whichOut)
{
  const int c = blockIdx.x, b = c / NS_, s = c % NS_;
  const int t = threadIdx.x, lane = t & 63, wv = t >> 6;

  unsigned wlo[64], whi[64];
  {
    const float* wr = prefW + t*256;
    #pragma unroll
    for (int i = 0; i < 32; ++i){
      float4 f = *(const float4*)(wr + 4*i);
      wlo[2*i]   = packbf(f.x, f.y);
      wlo[2*i+1] = packbf(f.z, f.w);
    }
    #pragma unroll
    for (int i = 0; i < 32; ++i){
      float4 f = *(const float4*)(wr + 128 + 4*i);
      whi[2*i]   = packbf(f.x, f.y);
      whi[2*i+1] = packbf(f.z, f.w);
    }
  }
  const float biast = prefB[t];
  float prev1 = 0.f;   // zold = 0 at step 0

  __shared__ float zc[128], znf[128];
  __shared__ __align__(16) unsigned xpk[64];
  __shared__ float sScale, sTotal;
  __shared__ float sTot[8];
  __shared__ int sFirst[8], sWhich;

  if (t < 128) zc[t] = latent[zi[b]*D_ + t];
  __syncthreads();

  for (int st = 0; st < T_; ++st){
    // --- std (ddof=1) of carry z, wave 0 only ---
    if (wv == 0){
      float v0 = zc[lane], v1 = zc[lane + 64];
      float sm = v0 + v1, sq = v0*v0 + v1*v1;
      #pragma unroll
      for (int m = 1; m < 64; m <<= 1){
        sm += __shfl_xor(sm, m, 64);
        sq += __shfl_xor(sq, m, 64);
      }
      if (lane == 0){
        float mean = sm * (1.f/128.f);
        float var  = (sq - 128.f*mean*mean) * (1.f/127.f);
        sScale = 0.113f / (1e-5f + sqrtf(var));
      }
    }
    __syncthreads();                                   // (1)
    const float sc = sScale;
    if (t < 64){
      float a  = zc[2*t]   * sc;
      float bb = zc[2*t+1] * sc;
      znf[2*t] = a; znf[2*t+1] = bb;
      xpk[t] = packbf(a, bb);
    }
    __syncthreads();                                   // (2)

    // --- matvec: pref[t] = prev1 + W[t,128:].znorm + b[t] ---
    float a1 = 0.f, a2 = 0.f;
    const uint4* xp4 = (const uint4*)xpk;
    #pragma unroll
    for (int i = 0; i < 16; ++i){
      uint4 xq = xp4[i];
      mac2(xq.x, wlo[4*i+0], whi[4*i+0], a1, a2);
      mac2(xq.y, wlo[4*i+1], whi[4*i+1], a1, a2);
      mac2(xq.z, wlo[4*i+2], whi[4*i+2], a1, a2);
      mac2(xq.w, wlo[4*i+3], whi[4*i+3], a1, a2);
    }
    const float pref = prev1 + a2 + biast;
    prev1 = a1;

    // --- softmax-cumsum-sample (logits tiny: skip max subtraction) ---
    float e = __expf(pref);
    float cs = e;
    #pragma unroll
    for (int d = 1; d < 64; d <<= 1){
      float v = __shfl_up(cs, (unsigned)d, 64);
      if (lane >= d) cs += v;
    }
    if (lane == 63) sTot[wv] = cs;
    __syncthreads();                                   // (3)
    if (t == 0){
      float off = 0.f;
      #pragma unroll
      for (int i = 0; i < 8; ++i){ float x = sTot[i]; sTot[i] = off; off += x; }
      sTotal = off;
    }
    __syncthreads();                                   // (4)
    const float rdv = rd[st*(B_*NS_) + b*NS_ + s];
    const float cum = cs + sTot[wv];
    const bool cond = rdv * sTotal < cum;              // rd < cumsum/total
    unsigned long long bal = __ballot(cond);
    if (lane == 0)
      sFirst[wv] = bal ? (wv*64 + __ffsll((unsigned long long)bal) - 1) : 0x7fffffff;
    __syncthreads();                                   // (5)
    if (t == 0){
      int w = 0x7fffffff;
      #pragma unroll
      for (int i = 0; i < 8; ++i) w = min(w, sFirst[i]);
      sWhich = (w == 0x7fffffff) ? 0 : w;              // argmax-of-all-false = 0
    }
    __syncthreads();                                   // (6)
    const int which = sWhich;
    if (t < 128) zc[t] = znf[t] + move[which*D_ + t];  // new carry z
    if (t == 0) whichOut[c*T_ + st] = which;
    __syncthreads();                                   // (7)
  }
}

// ---------------------------------------------------------------------------
// Phase C: yp[c,t] = move[which].vocabW[y] + vb[y] - log(partial[which])
// ---------------------------------------------------------------------------
__global__ __launch_bounds__(256) void dots_kernel(
    const int* __restrict__ whichIn, const int* __restrict__ y,
    const float* __restrict__ move, const float* __restrict__ vw,
    const float* __restrict__ vb, const float* __restrict__ partial,
    float* __restrict__ yp)
{
  const int c = blockIdx.x, b = c / NS_;
  const int wv = threadIdx.x >> 6, lane = threadIdx.x & 63;
  for (int st = wv; st < T_; st += 4){
    const int w  = whichIn[c*T_ + st];
    const int yr = y[b*T_ + st];
    const float* mp = move + w*D_;
    const float* vp = vw + yr*D_;
    float p = mp[lane]*vp[lane] + mp[lane+64]*vp[lane+64];
    #pragma unroll
    for (int m = 1; m < 64; m <<= 1) p += __shfl_xor(p, m, 64);
    if (lane == 0) yp[c*T_ + st] = p + vb[yr] - logf(partial[w]);
  }
}

// ---------------------------------------------------------------------------
// Phase D: out[b,t] = mean over 10 samples
// ---------------------------------------------------------------------------
__global__ void final_kernel(const float* __restrict__ yp, float* __restrict__ out){
  const int i = threadIdx.x;            // 512
  const int b = i >> 5, tt = i & 31;
  float acc = 0.f;
  #pragma unroll
  for (int s = 0; s < NS_; ++s) acc += yp[(b*NS_ + s)*T_ + tt];
  out[i] = acc * (1.f/NS_);
}

extern "C" void kernel_launch(void* const* d_in, const int* in_sizes, int n_in,
                              void* d_out, int out_size, void* d_ws, size_t ws_size,
                              hipStream_t stream)
{
  const int*   zi     = (const int*)d_in[0];
  const int*   y      = (const int*)d_in[1];
  const float* rd     = (const float*)d_in[2];
  const float* latent = (const float*)d_in[3];
  const float* prefW  = (const float*)d_in[4];
  const float* prefB  = (const float*)d_in[5];
  const float* move   = (const float*)d_in[6];
  const float* vw     = (const float*)d_in[7];
  const float* vb     = (const float*)d_in[8];
  float* out = (float*)d_out;

  float* partial = (float*)d_ws;                                   // 512 f32
  int*   which   = (int*)((char*)d_ws + 2048);                     // 160*32 i32
  float* yp      = (float*)((char*)d_ws + 2048 + NCHAIN*T_*4);     // 160*32 f32

  hipMemsetAsync(partial, 0, ST_*sizeof(float), stream);           // fresh each call
  hipLaunchKernelGGL(logz_kernel, dim3(125, 8), dim3(256), 0, stream,
                     move, vw, vb, partial);
  hipLaunchKernelGGL(scan_kernel, dim3(NCHAIN), dim3(512), 0, stream,
                     zi, latent, prefW, prefB, move, rd, which);
  hipLaunchKernelGGL(dots_kernel, dim3(NCHAIN), dim3(256), 0, stream,
                     which, y, move, vw, vb, partial, yp);
  hipLaunchKernelGGL(final_kernel, dim3(1), dim3(512), 0, stream, yp, out);
}

// Round 2
// 1364.186 us; speedup vs baseline: 1.1542x; 1.1542x over previous
//
#include <hip/hip_runtime.h>
#include <hip/hip_bf16.h>

#define B_ 16
#define T_ 32
#define NS_ 10
#define D_ 128
#define ST_ 512
#define V_ 32000
#define NCHAIN 160

using short8 = __attribute__((ext_vector_type(8))) short;
using f32x4  = __attribute__((ext_vector_type(4))) float;

__device__ __forceinline__ unsigned short f2bf(float f){
  unsigned u = __float_as_uint(f);
  u += 0x7FFFu + ((u >> 16) & 1u);          // RNE to bf16
  return (unsigned short)(u >> 16);
}
__device__ __forceinline__ unsigned packbf(float a, float b){
  return ((unsigned)f2bf(b) << 16) | (unsigned)f2bf(a);
}
__device__ __forceinline__ void mac2(unsigned ux, unsigned ul, unsigned uh,
                                     float& a1, float& a2){
  const float x0 = __uint_as_float(ux << 16);
  const float x1 = __uint_as_float(ux & 0xFFFF0000u);
  const float l0 = __uint_as_float(ul << 16);
  const float l1 = __uint_as_float(ul & 0xFFFF0000u);
  const float h0 = __uint_as_float(uh << 16);
  const float h1 = __uint_as_float(uh & 0xFFFF0000u);
  a1 = fmaf(x1, l1, fmaf(x0, l0, a1));
  a2 = fmaf(x1, h1, fmaf(x0, h0, a2));
}

// ---------------------------------------------------------------------------
// Phase B: partial[s] = sum_v exp(move_s . vocabW_v + vb_v)   (512x32000 GEMM)
// ---------------------------------------------------------------------------
__global__ __launch_bounds__(256) void logz_kernel(
    const float* __restrict__ move, const float* __restrict__ vw,
    const float* __restrict__ vb, float* __restrict__ partial)
{
  const int sg = blockIdx.y;
  const int vc = blockIdx.x;
  const int wv = threadIdx.x >> 6;
  const int lane = threadIdx.x & 63;
  const int c16 = lane & 15, q = lane >> 4;

  __shared__ float les[64];
  if (threadIdx.x < 64) les[threadIdx.x] = 0.f;

  short8 afr[4][4];
  #pragma unroll
  for (int rt = 0; rt < 4; ++rt){
    const float* mp = move + (sg*64 + rt*16 + c16)*D_ + q*8;
    #pragma unroll
    for (int kk = 0; kk < 4; ++kk){
      float4 f0 = *(const float4*)(mp + kk*32);
      float4 f1 = *(const float4*)(mp + kk*32 + 4);
      short8 a;
      a[0]=(short)f2bf(f0.x); a[1]=(short)f2bf(f0.y);
      a[2]=(short)f2bf(f0.z); a[3]=(short)f2bf(f0.w);
      a[4]=(short)f2bf(f1.x); a[5]=(short)f2bf(f1.y);
      a[6]=(short)f2bf(f1.z); a[7]=(short)f2bf(f1.w);
      afr[rt][kk] = a;
    }
  }
  __syncthreads();

  float es[4][4] = {{0.f,0.f,0.f,0.f},{0.f,0.f,0.f,0.f},
                    {0.f,0.f,0.f,0.f},{0.f,0.f,0.f,0.f}};

  for (int it = 0; it < 4; ++it){
    const int v  = vc*256 + it*64 + wv*16 + c16;
    const float* wp = vw + v*D_ + q*8;
    short8 bfr[4];
    #pragma unroll
    for (int kk = 0; kk < 4; ++kk){
      float4 f0 = *(const float4*)(wp + kk*32);
      float4 f1 = *(const float4*)(wp + kk*32 + 4);
      short8 bb;
      bb[0]=(short)f2bf(f0.x); bb[1]=(short)f2bf(f0.y);
      bb[2]=(short)f2bf(f0.z); bb[3]=(short)f2bf(f0.w);
      bb[4]=(short)f2bf(f1.x); bb[5]=(short)f2bf(f1.y);
      bb[6]=(short)f2bf(f1.z); bb[7]=(short)f2bf(f1.w);
      bfr[kk] = bb;
    }
    const float bias = vb[v];
    #pragma unroll
    for (int rt = 0; rt < 4; ++rt){
      f32x4 acc = {0.f, 0.f, 0.f, 0.f};
      #pragma unroll
      for (int kk = 0; kk < 4; ++kk)
        acc = __builtin_amdgcn_mfma_f32_16x16x32_bf16(afr[rt][kk], bfr[kk], acc, 0, 0, 0);
      #pragma unroll
      for (int r = 0; r < 4; ++r)
        es[rt][r] += __expf(acc[r] + bias);
    }
  }
  #pragma unroll
  for (int m = 1; m < 16; m <<= 1){
    #pragma unroll
    for (int rt = 0; rt < 4; ++rt)
      #pragma unroll
      for (int r = 0; r < 4; ++r)
        es[rt][r] += __shfl_xor(es[rt][r], m, 64);
  }
  if (c16 == 0){
    #pragma unroll
    for (int rt = 0; rt < 4; ++rt)
      #pragma unroll
      for (int r = 0; r < 4; ++r)
        atomicAdd(&les[rt*16 + q*4 + r], es[rt][r]);
  }
  __syncthreads();
  if (threadIdx.x < 64) atomicAdd(&partial[sg*64 + threadIdx.x], les[threadIdx.x]);
}

// ---------------------------------------------------------------------------
// Phase A: sequential 32-step scan. One block per (b,sample) chain.
// 512 threads; thread t owns state row t of state_pref_W, bf16-packed in
// 128 VGPRs (launch_bounds(512,2) -> 256-VGPR cap, no spill).
// prev1 = W[:, :128].znorm from previous step == W[:, :128].zold this step.
// 4 barriers/step.
// ---------------------------------------------------------------------------
__global__ __launch_bounds__(512, 2) void scan_kernel(
    const int* __restrict__ zi, const float* __restrict__ latent,
    const float* __restrict__ prefW, const float* __restrict__ prefB,
    const float* __restrict__ move, const float* __restrict__ rd,
    int* __restrict__ whichOut)
{
  const int c = blockIdx.x, b = c / NS_, s = c % NS_;
  const int t = threadIdx.x, lane = t & 63, wv = t >> 6;

  unsigned wlo[64], whi[64];
  {
    const float* wr = prefW + t*256;
    #pragma unroll
    for (int i = 0; i < 32; ++i){
      float4 f = *(const float4*)(wr + 4*i);
      wlo[2*i]   = packbf(f.x, f.y);
      wlo[2*i+1] = packbf(f.z, f.w);
    }
    #pragma unroll
    for (int i = 0; i < 32; ++i){
      float4 f = *(const float4*)(wr + 128 + 4*i);
      whi[2*i]   = packbf(f.x, f.y);
      whi[2*i+1] = packbf(f.z, f.w);
    }
  }
  const float biast = prefB[t];
  float prev1 = 0.f;   // zold = 0 at step 0

  __shared__ float zc[128], znf[128];
  __shared__ __align__(16) unsigned xpk[64];
  __shared__ float sTot[8];
  __shared__ int sFirst[8];
  __shared__ float sRd[T_];

  if (t < 128) zc[t] = latent[zi[b]*D_ + t];
  if (t < T_)  sRd[t] = rd[t*(B_*NS_) + b*NS_ + s];
  __syncthreads();

  for (int st = 0; st < T_; ++st){
    // --- std (ddof=1) of carry z, computed redundantly in every wave ---
    float v0 = zc[lane], v1 = zc[lane + 64];
    float sm = v0 + v1, sq = v0*v0 + v1*v1;
    #pragma unroll
    for (int m = 1; m < 64; m <<= 1){
      sm += __shfl_xor(sm, m, 64);
      sq += __shfl_xor(sq, m, 64);
    }
    const float mean = sm * (1.f/128.f);
    const float var  = (sq - 128.f*mean*mean) * (1.f/127.f);
    const float sc   = 0.113f / (1e-5f + sqrtf(var));
    if (t < 64){
      float a  = zc[2*t]   * sc;
      float bb = zc[2*t+1] * sc;
      znf[2*t] = a; znf[2*t+1] = bb;
      xpk[t] = packbf(a, bb);
    }
    __syncthreads();                                   // (A)

    // --- matvec: pref[t] = prev1 + W[t,128:].znorm + b[t] ---
    float a1 = 0.f, a2 = 0.f;
    const uint4* xp4 = (const uint4*)xpk;
    #pragma unroll
    for (int i = 0; i < 16; ++i){
      uint4 xq = xp4[i];
      mac2(xq.x, wlo[4*i+0], whi[4*i+0], a1, a2);
      mac2(xq.y, wlo[4*i+1], whi[4*i+1], a1, a2);
      mac2(xq.z, wlo[4*i+2], whi[4*i+2], a1, a2);
      mac2(xq.w, wlo[4*i+3], whi[4*i+3], a1, a2);
    }
    const float pref = prev1 + a2 + biast;
    prev1 = a1;

    // --- softmax-cumsum-sample (logits tiny: skip max subtraction) ---
    float e = __expf(pref);
    float cs = e;
    #pragma unroll
    for (int d = 1; d < 64; d <<= 1){
      float v = __shfl_up(cs, (unsigned)d, 64);
      if (lane >= d) cs += v;
    }
    if (lane == 63) sTot[wv] = cs;
    __syncthreads();                                   // (B)
    float off = 0.f, total = 0.f;
    #pragma unroll
    for (int i = 0; i < 8; ++i){
      float x = sTot[i];
      if (i < wv) off += x;
      total += x;
    }
    const float rdv = sRd[st];
    const bool cond = rdv * total < off + cs;          // rd < cumsum/total
    unsigned long long bal = __ballot(cond);
    if (lane == 0)
      sFirst[wv] = bal ? (wv*64 + __ffsll((unsigned long long)bal) - 1) : 0x7fffffff;
    __syncthreads();                                   // (C)
    int w = 0x7fffffff;
    #pragma unroll
    for (int i = 0; i < 8; ++i) w = min(w, sFirst[i]);
    const int which = (w == 0x7fffffff) ? 0 : w;       // argmax-of-all-false = 0
    if (t < 128) zc[t] = znf[t] + move[which*D_ + t];  // new carry z
    if (t == 0) whichOut[c*T_ + st] = which;
    __syncthreads();                                   // (D)
  }
}

// ---------------------------------------------------------------------------
// Phase C: yp[c,t] = move[which].vocabW[y] + vb[y] - log(partial[which])
// ---------------------------------------------------------------------------
__global__ __launch_bounds__(256) void dots_kernel(
    const int* __restrict__ whichIn, const int* __restrict__ y,
    const float* __restrict__ move, const float* __restrict__ vw,
    const float* __restrict__ vb, const float* __restrict__ partial,
    float* __restrict__ yp)
{
  const int c = blockIdx.x, b = c / NS_;
  const int wv = threadIdx.x >> 6, lane = threadIdx.x & 63;
  for (int st = wv; st < T_; st += 4){
    const int w  = whichIn[c*T_ + st];
    const int yr = y[b*T_ + st];
    const float* mp = move + w*D_;
    const float* vp = vw + yr*D_;
    float p = mp[lane]*vp[lane] + mp[lane+64]*vp[lane+64];
    #pragma unroll
    for (int m = 1; m < 64; m <<= 1) p += __shfl_xor(p, m, 64);
    if (lane == 0) yp[c*T_ + st] = p + vb[yr] - logf(partial[w]);
  }
}

// ---------------------------------------------------------------------------
// Phase D: out[b,t] = mean over 10 samples
// ---------------------------------------------------------------------------
__global__ void final_kernel(const float* __restrict__ yp, float* __restrict__ out){
  const int i = threadIdx.x;            // 512
  const int b = i >> 5, tt = i & 31;
  float acc = 0.f;
  #pragma unroll
  for (int s = 0; s < NS_; ++s) acc += yp[(b*NS_ + s)*T_ + tt];
  out[i] = acc * (1.f/NS_);
}

extern "C" void kernel_launch(void* const* d_in, const int* in_sizes, int n_in,
                              void* d_out, int out_size, void* d_ws, size_t ws_size,
                              hipStream_t stream)
{
  const int*   zi     = (const int*)d_in[0];
  const int*   y      = (const int*)d_in[1];
  const float* rd     = (const float*)d_in[2];
  const float* latent = (const float*)d_in[3];
  const float* prefW  = (const float*)d_in[4];
  const float* prefB  = (const float*)d_in[5];
  const float* move   = (const float*)d_in[6];
  const float* vw     = (const float*)d_in[7];
  const float* vb     = (const float*)d_in[8];
  float* out = (float*)d_out;

  float* partial = (float*)d_ws;                                   // 512 f32
  int*   which   = (int*)((char*)d_ws + 2048);                     // 160*32 i32
  float* yp      = (float*)((char*)d_ws + 2048 + NCHAIN*T_*4);     // 160*32 f32

  hipMemsetAsync(partial, 0, ST_*sizeof(float), stream);
  hipLaunchKernelGGL(logz_kernel, dim3(125, 8), dim3(256), 0, stream,
                     move, vw, vb, partial);
  hipLaunchKernelGGL(scan_kernel, dim3(NCHAIN), dim3(512), 0, stream,
                     zi, latent, prefW, prefB, move, rd, which);
  hipLaunchKernelGGL(dots_kernel, dim3(NCHAIN), dim3(256), 0, stream,
                     which, y, move, vw, vb, partial, yp);
  hipLaunchKernelGGL(final_kernel, dim3(1), dim3(512), 0, stream, yp, out);
}

// Round 3
// 128.812 us; speedup vs baseline: 12.2233x; 10.5905x over previous
//
#include <hip/hip_runtime.h>
#include <hip/hip_bf16.h>

#define B_ 16
#define T_ 32
#define NS_ 10
#define D_ 128
#define ST_ 512
#define V_ 32000
#define NCHAIN 160

using short8  = __attribute__((ext_vector_type(8))) short;
using f32x4   = __attribute__((ext_vector_type(4))) float;
using uintx16 = __attribute__((ext_vector_type(16))) unsigned;
using half2v  = __attribute__((ext_vector_type(2))) _Float16;

__device__ __forceinline__ unsigned short f2bf(float f){
  unsigned u = __float_as_uint(f);
  u += 0x7FFFu + ((u >> 16) & 1u);          // RNE to bf16
  return (unsigned short)(u >> 16);
}
__device__ __forceinline__ unsigned packbf(float a, float b){
  return ((unsigned)f2bf(b) << 16) | (unsigned)f2bf(a);
}
// f16 pack (f16 mantissa > bf16 mantissa: better accuracy for small weights)
__device__ __forceinline__ unsigned packh(float a, float b){
  unsigned short ua = __builtin_bit_cast(unsigned short, (_Float16)a);
  unsigned short ub = __builtin_bit_cast(unsigned short, (_Float16)b);
  return ((unsigned)ub << 16) | ua;
}
__device__ __forceinline__ half2v u2h2(unsigned u){
  return __builtin_bit_cast(half2v, u);
}
__device__ __forceinline__ void mach2(unsigned ux, unsigned ul, unsigned uh,
                                      float& a1, float& a2){
#if __has_builtin(__builtin_amdgcn_fdot2)
  a1 = __builtin_amdgcn_fdot2(u2h2(ux), u2h2(ul), a1, false);
  a2 = __builtin_amdgcn_fdot2(u2h2(ux), u2h2(uh), a2, false);
#else
  half2v x = u2h2(ux), l = u2h2(ul), h = u2h2(uh);
  a1 += (float)x[0]*(float)l[0] + (float)x[1]*(float)l[1];
  a2 += (float)x[0]*(float)h[0] + (float)x[1]*(float)h[1];
#endif
}

// ---------------------------------------------------------------------------
// Phase B: partial[s] = sum_v exp(move_s . vocabW_v + vb_v)   (512x32000 GEMM)
// ---------------------------------------------------------------------------
__global__ __launch_bounds__(256) void logz_kernel(
    const float* __restrict__ move, const float* __restrict__ vw,
    const float* __restrict__ vb, float* __restrict__ partial)
{
  const int sg = blockIdx.y;
  const int vc = blockIdx.x;
  const int wv = threadIdx.x >> 6;
  const int lane = threadIdx.x & 63;
  const int c16 = lane & 15, q = lane >> 4;

  __shared__ float les[64];
  if (threadIdx.x < 64) les[threadIdx.x] = 0.f;

  short8 afr[4][4];
  #pragma unroll
  for (int rt = 0; rt < 4; ++rt){
    const float* mp = move + (sg*64 + rt*16 + c16)*D_ + q*8;
    #pragma unroll
    for (int kk = 0; kk < 4; ++kk){
      float4 f0 = *(const float4*)(mp + kk*32);
      float4 f1 = *(const float4*)(mp + kk*32 + 4);
      short8 a;
      a[0]=(short)f2bf(f0.x); a[1]=(short)f2bf(f0.y);
      a[2]=(short)f2bf(f0.z); a[3]=(short)f2bf(f0.w);
      a[4]=(short)f2bf(f1.x); a[5]=(short)f2bf(f1.y);
      a[6]=(short)f2bf(f1.z); a[7]=(short)f2bf(f1.w);
      afr[rt][kk] = a;
    }
  }
  __syncthreads();

  float es[4][4] = {{0.f,0.f,0.f,0.f},{0.f,0.f,0.f,0.f},
                    {0.f,0.f,0.f,0.f},{0.f,0.f,0.f,0.f}};

  for (int it = 0; it < 4; ++it){
    const int v  = vc*256 + it*64 + wv*16 + c16;
    const float* wp = vw + v*D_ + q*8;
    short8 bfr[4];
    #pragma unroll
    for (int kk = 0; kk < 4; ++kk){
      float4 f0 = *(const float4*)(wp + kk*32);
      float4 f1 = *(const float4*)(wp + kk*32 + 4);
      short8 bb;
      bb[0]=(short)f2bf(f0.x); bb[1]=(short)f2bf(f0.y);
      bb[2]=(short)f2bf(f0.z); bb[3]=(short)f2bf(f0.w);
      bb[4]=(short)f2bf(f1.x); bb[5]=(short)f2bf(f1.y);
      bb[6]=(short)f2bf(f1.z); bb[7]=(short)f2bf(f1.w);
      bfr[kk] = bb;
    }
    const float bias = vb[v];
    #pragma unroll
    for (int rt = 0; rt < 4; ++rt){
      f32x4 acc = {0.f, 0.f, 0.f, 0.f};
      #pragma unroll
      for (int kk = 0; kk < 4; ++kk)
        acc = __builtin_amdgcn_mfma_f32_16x16x32_bf16(afr[rt][kk], bfr[kk], acc, 0, 0, 0);
      #pragma unroll
      for (int r = 0; r < 4; ++r)
        es[rt][r] += __expf(acc[r] + bias);
    }
  }
  #pragma unroll
  for (int m = 1; m < 16; m <<= 1){
    #pragma unroll
    for (int rt = 0; rt < 4; ++rt)
      #pragma unroll
      for (int r = 0; r < 4; ++r)
        es[rt][r] += __shfl_xor(es[rt][r], m, 64);
  }
  if (c16 == 0){
    #pragma unroll
    for (int rt = 0; rt < 4; ++rt)
      #pragma unroll
      for (int r = 0; r < 4; ++r)
        atomicAdd(&les[rt*16 + q*4 + r], es[rt][r]);
  }
  __syncthreads();
  if (threadIdx.x < 64) atomicAdd(&partial[sg*64 + threadIdx.x], les[threadIdx.x]);
}

// ---------------------------------------------------------------------------
// Phase A: sequential 32-step scan. One block per (b,sample) chain.
// 512 threads; thread t owns state row t of state_pref_W as f16 pairs held in
// EIGHT ext_vector_type(16) SSA VALUES (128 VGPRs) — vector values cannot be
// demoted to scratch (the R1 kernel's arrays were never promoted: VGPR=128
// with 790MB scratch FETCH). waves_per_eu(1) gives regalloc a 512-VGPR budget.
// prev1 = W[:, :128].znorm of previous step == W[:, :128].zold this step.
// ---------------------------------------------------------------------------
__global__ __launch_bounds__(512) __attribute__((amdgpu_waves_per_eu(1)))
void scan_kernel(
    const int* __restrict__ zi, const float* __restrict__ latent,
    const float* __restrict__ prefW, const float* __restrict__ prefB,
    const float* __restrict__ move, const float* __restrict__ rd,
    int* __restrict__ whichOut)
{
  const int c = blockIdx.x, b = c / NS_, s = c % NS_;
  const int t = threadIdx.x, lane = t & 63, wv = t >> 6;

  uintx16 wl0, wl1, wl2, wl3, wh0, wh1, wh2, wh3;
  {
    const float* wr = prefW + t*256;
#define LOADV(VEC, OFF) { \
    _Pragma("unroll") \
    for (int i = 0; i < 8; ++i){ \
      float4 f = *(const float4*)(wr + (OFF) + 4*i); \
      VEC[2*i]   = packh(f.x, f.y); \
      VEC[2*i+1] = packh(f.z, f.w); \
    } }
    LOADV(wl0,   0) LOADV(wl1,  32) LOADV(wl2,  64) LOADV(wl3,  96)
    LOADV(wh0, 128) LOADV(wh1, 160) LOADV(wh2, 192) LOADV(wh3, 224)
#undef LOADV
  }
  const float biast = prefB[t];
  float prev1 = 0.f;   // zold = 0 at step 0

  __shared__ float zc[128], znf[128];
  __shared__ __align__(16) unsigned xpk[64];
  __shared__ float sTot[8];
  __shared__ int sFirst[8];
  __shared__ float sRd[T_];

  if (t < 128) zc[t] = latent[zi[b]*D_ + t];
  if (t < T_)  sRd[t] = rd[t*(B_*NS_) + b*NS_ + s];
  __syncthreads();

  for (int st = 0; st < T_; ++st){
    // --- std (ddof=1) of carry z, computed redundantly in every wave ---
    float v0 = zc[lane], v1 = zc[lane + 64];
    float sm = v0 + v1, sq = v0*v0 + v1*v1;
    #pragma unroll
    for (int m = 1; m < 64; m <<= 1){
      sm += __shfl_xor(sm, m, 64);
      sq += __shfl_xor(sq, m, 64);
    }
    const float mean = sm * (1.f/128.f);
    const float var  = (sq - 128.f*mean*mean) * (1.f/127.f);
    const float sc   = 0.113f / (1e-5f + sqrtf(var));
    if (t < 64){
      float a  = zc[2*t]   * sc;
      float bb = zc[2*t+1] * sc;
      znf[2*t] = a; znf[2*t+1] = bb;
      xpk[t] = packh(a, bb);
    }
    __syncthreads();                                   // (A)

    // --- matvec: pref[t] = prev1 + W[t,128:].znorm + b[t] ---
    float a1 = 0.f, a2 = 0.f;
    const uint4* xp4 = (const uint4*)xpk;
#define MACQ(WL, WH, I, E) { uint4 xq = xp4[I]; \
    mach2(xq.x, WL[(E)+0], WH[(E)+0], a1, a2); \
    mach2(xq.y, WL[(E)+1], WH[(E)+1], a1, a2); \
    mach2(xq.z, WL[(E)+2], WH[(E)+2], a1, a2); \
    mach2(xq.w, WL[(E)+3], WH[(E)+3], a1, a2); }
#define MACB(WL, WH, IB) MACQ(WL,WH,(IB)+0,0) MACQ(WL,WH,(IB)+1,4) \
                         MACQ(WL,WH,(IB)+2,8) MACQ(WL,WH,(IB)+3,12)
    MACB(wl0, wh0, 0) MACB(wl1, wh1, 4) MACB(wl2, wh2, 8) MACB(wl3, wh3, 12)
#undef MACB
#undef MACQ
    const float pref = prev1 + a2 + biast;
    prev1 = a1;

    // --- softmax-cumsum-sample (logits tiny: skip max subtraction) ---
    float e = __expf(pref);
    float cs = e;
    #pragma unroll
    for (int d = 1; d < 64; d <<= 1){
      float v = __shfl_up(cs, (unsigned)d, 64);
      if (lane >= d) cs += v;
    }
    if (lane == 63) sTot[wv] = cs;
    __syncthreads();                                   // (B)
    float off = 0.f, total = 0.f;
    #pragma unroll
    for (int i = 0; i < 8; ++i){
      float x = sTot[i];
      if (i < wv) off += x;
      total += x;
    }
    const float rdv = sRd[st];
    const bool cond = rdv * total < off + cs;          // rd < cumsum/total
    unsigned long long bal = __ballot(cond);
    if (lane == 0)
      sFirst[wv] = bal ? (wv*64 + __ffsll((unsigned long long)bal) - 1) : 0x7fffffff;
    __syncthreads();                                   // (C)
    int w = 0x7fffffff;
    #pragma unroll
    for (int i = 0; i < 8; ++i) w = min(w, sFirst[i]);
    const int which = (w == 0x7fffffff) ? 0 : w;       // argmax-of-all-false = 0
    if (t < 128) zc[t] = znf[t] + move[which*D_ + t];  // new carry z
    if (t == 0) whichOut[c*T_ + st] = which;
    __syncthreads();                                   // (D)
  }
}

// ---------------------------------------------------------------------------
// Phase C: yp[c,t] = move[which].vocabW[y] + vb[y] - log(partial[which])
// ---------------------------------------------------------------------------
__global__ __launch_bounds__(256) void dots_kernel(
    const int* __restrict__ whichIn, const int* __restrict__ y,
    const float* __restrict__ move, const float* __restrict__ vw,
    const float* __restrict__ vb, const float* __restrict__ partial,
    float* __restrict__ yp)
{
  const int c = blockIdx.x, b = c / NS_;
  const int wv = threadIdx.x >> 6, lane = threadIdx.x & 63;
  for (int st = wv; st < T_; st += 4){
    const int w  = whichIn[c*T_ + st];
    const int yr = y[b*T_ + st];
    const float* mp = move + w*D_;
    const float* vp = vw + yr*D_;
    float p = mp[lane]*vp[lane] + mp[lane+64]*vp[lane+64];
    #pragma unroll
    for (int m = 1; m < 64; m <<= 1) p += __shfl_xor(p, m, 64);
    if (lane == 0) yp[c*T_ + st] = p + vb[yr] - logf(partial[w]);
  }
}

// ---------------------------------------------------------------------------
// Phase D: out[b,t] = mean over 10 samples
// ---------------------------------------------------------------------------
__global__ void final_kernel(const float* __restrict__ yp, float* __restrict__ out){
  const int i = threadIdx.x;            // 512
  const int b = i >> 5, tt = i & 31;
  float acc = 0.f;
  #pragma unroll
  for (int s = 0; s < NS_; ++s) acc += yp[(b*NS_ + s)*T_ + tt];
  out[i] = acc * (1.f/NS_);
}

extern "C" void kernel_launch(void* const* d_in, const int* in_sizes, int n_in,
                              void* d_out, int out_size, void* d_ws, size_t ws_size,
                              hipStream_t stream)
{
  const int*   zi     = (const int*)d_in[0];
  const int*   y      = (const int*)d_in[1];
  const float* rd     = (const float*)d_in[2];
  const float* latent = (const float*)d_in[3];
  const float* prefW  = (const float*)d_in[4];
  const float* prefB  = (const float*)d_in[5];
  const float* move   = (const float*)d_in[6];
  const float* vw     = (const float*)d_in[7];
  const float* vb     = (const float*)d_in[8];
  float* out = (float*)d_out;

  float* partial = (float*)d_ws;                                   // 512 f32
  int*   which   = (int*)((char*)d_ws + 2048);                     // 160*32 i32
  float* yp      = (float*)((char*)d_ws + 2048 + NCHAIN*T_*4);     // 160*32 f32

  hipMemsetAsync(partial, 0, ST_*sizeof(float), stream);
  hipLaunchKernelGGL(logz_kernel, dim3(125, 8), dim3(256), 0, stream,
                     move, vw, vb, partial);
  hipLaunchKernelGGL(scan_kernel, dim3(NCHAIN), dim3(512), 0, stream,
                     zi, latent, prefW, prefB, move, rd, which);
  hipLaunchKernelGGL(dots_kernel, dim3(NCHAIN), dim3(256), 0, stream,
                     which, y, move, vw, vb, partial, yp);
  hipLaunchKernelGGL(final_kernel, dim3(1), dim3(512), 0, stream, yp, out);
}